// Round 6
// baseline (127.561 us; speedup 1.0000x reference)
//
#include <hip/hip_runtime.h>
#include <hip/hip_fp16.h>
#include <cmath>

// Encoder_conv2: 5-level multires feature encoder.
//   Kernel A (tiny): depthwise 3x3 conv + tanh -> PADDED fp16 texel table in
//     d_ws. Layout per level: [cell][y][x][c4], dims (R+1)x(R+1), last
//     row/col duplicated -> clamp-free bilinear cornering.
//   Kernel B: stage table to LDS, sample 256-point tiles; each thread writes
//     its 20-float row to an LDS stage tile, then the block copies the tile
//     to global with lane-consecutive float4 stores (fully coalesced).
//
// R6 rationale: R1-R5 showed the sampler pinned at ~43 us across wildly
// different gather structures and occupancies -> not LDS/VALU/occupancy
// bound. Invariant was the 80B-stride 16B/lane global stores (64 lines per
// store instr, partial-sector writes; R4 measured 1.44 TB/s = 18% peak on a
// pure-write stream). This round coalesces stores via LDS transpose.

#define NTH 256
#define PPT 4   // 977 blocks of 1024-point tiles

// padded per-level sizes: 8*(R+1)^2 elements (2 cells * 4 ch * (R+1)^2)
// RES = [8,12,20,18,32] -> 648,1352,3528,2888,8712 ; total 17128 el = 34256 B
constexpr int PTOT = 17128;
#define OFF0 0
#define OFF1 648
#define OFF2 2000
#define OFF3 5528
#define OFF4 8416

// ---------------- Kernel A: conv 3x3 (SAME) + tanh -> padded fp16 table ----
template<int R>
__device__ __forceinline__ void conv_level(const float* __restrict__ F,
                                           const float* __restrict__ w,
                                           __half* __restrict__ dst,
                                           int tid, int nth)
{
    constexpr int P = R + 1;
    const int n = 8 * P * P;
    for (int i = tid; i < n; i += nth) {
        int c    = i & 3;
        int pos  = i >> 2;
        int cell = (pos >= P * P) ? 1 : 0;
        int rem  = pos - cell * P * P;
        int py   = rem / P;               // P compile-time: magic-mul
        int px   = rem - py * P;
        int yy   = min(py, R - 1);        // duplicate last row/col (padding)
        int xx   = min(px, R - 1);
        const float* Fc = F + (cell * 4 + c) * R * R;
        float acc = 0.f;
#pragma unroll
        for (int ky = 0; ky < 3; ++ky) {
#pragma unroll
            for (int kx = 0; kx < 3; ++kx) {
                int sy = yy + ky - 1, sx = xx + kx - 1;
                if ((unsigned)sy < (unsigned)R && (unsigned)sx < (unsigned)R)
                    acc = fmaf(w[c * 9 + ky * 3 + kx], Fc[sy * R + sx], acc);
            }
        }
        dst[(cell * P * P + py * P + px) * 4 + c] = __float2half(tanhf(acc));
    }
}

__global__ void conv_kernel(const float* __restrict__ F0, const float* __restrict__ F1,
                            const float* __restrict__ F2, const float* __restrict__ F3,
                            const float* __restrict__ F4, const float* __restrict__ w,
                            __half* __restrict__ tab)
{
    int tid = blockIdx.x * blockDim.x + threadIdx.x;
    int nth = gridDim.x * blockDim.x;
    conv_level<8 >(F0, w, tab + OFF0, tid, nth);
    conv_level<12>(F1, w, tab + OFF1, tid, nth);
    conv_level<20>(F2, w, tab + OFF2, tid, nth);
    conv_level<18>(F3, w, tab + OFF3, tid, nth);
    conv_level<32>(F4, w, tab + OFF4, tid, nth);
}

// ---------------- Kernel B: bilinear sampling -------------------------------
__device__ __forceinline__ float4 cvt4(uint2 raw)
{
    __half2 lo = *(__half2*)&raw.x;
    __half2 hi = *(__half2*)&raw.y;
    float2 f01 = __half22float2(lo);
    float2 f23 = __half22float2(hi);
    return make_float4(f01.x, f01.y, f23.x, f23.y);
}

template<int R>
__device__ __forceinline__ float4 sample_level(const __half* __restrict__ lt,
                                               float px, float py)
{
    constexpr int P = R + 1;
    // ix = (gx+1)*0.5*(R-1) with gx = 2x-1  ==  x*(R-1); px,py in [0,1]
    float fx = px * (float)(R - 1);
    float fy = py * (float)(R - 1);
    float4 acc = make_float4(0.f, 0.f, 0.f, 0.f);
#pragma unroll
    for (int cell = 0; cell < 2; ++cell) {
        float ixc = fx + 0.5f * (float)cell;   // off = cell/n_cells
        float iyc = fy + 0.5f * (float)cell;
        float fx0 = floorf(ixc);
        float fy0 = floorf(iyc);
        float wx = ixc - fx0;
        float wy = iyc - fy0;
        int ix0 = (int)fx0;                    // in [0, R-1]; pad handles +1
        int iy0 = (int)fy0;
        const __half* base = lt + (size_t)(cell * P * P + iy0 * P + ix0) * 4;
        // corner pairs: DS-combiner merges each row pair into ds_read2_b64
        uint2 t00 = *(const uint2*)(base);
        uint2 t01 = *(const uint2*)(base + 4);
        uint2 t10 = *(const uint2*)(base + P * 4);
        uint2 t11 = *(const uint2*)(base + P * 4 + 4);
        float4 nw = cvt4(t00), ne = cvt4(t01), sw = cvt4(t10), se = cvt4(t11);
        float u = 1.f - wx, v = 1.f - wy;
        float wnw = u * v, wne = wx * v, wsw = u * wy, wse = wx * wy;
        acc.x = fmaf(wnw, nw.x, acc.x); acc.x = fmaf(wne, ne.x, acc.x);
        acc.x = fmaf(wsw, sw.x, acc.x); acc.x = fmaf(wse, se.x, acc.x);
        acc.y = fmaf(wnw, nw.y, acc.y); acc.y = fmaf(wne, ne.y, acc.y);
        acc.y = fmaf(wsw, sw.y, acc.y); acc.y = fmaf(wse, se.y, acc.y);
        acc.z = fmaf(wnw, nw.z, acc.z); acc.z = fmaf(wne, ne.z, acc.z);
        acc.z = fmaf(wsw, sw.z, acc.z); acc.z = fmaf(wse, se.z, acc.z);
        acc.w = fmaf(wnw, nw.w, acc.w); acc.w = fmaf(wse, se.w, acc.w);
        acc.w = fmaf(wsw, sw.w, acc.w); acc.w = fmaf(wne, ne.w, acc.w);
    }
    return acc;
}

// Per-block body: sample PPT tiles of NTH points, staging each tile's output
// rows in LDS, then copying out with coalesced float4 stores.
__device__ __forceinline__ void sample_body(const __half* lds, float* stage,
                                            const float* __restrict__ x,
                                            const float* __restrict__ y,
                                            float* __restrict__ out, int npts)
{
    const int tid = threadIdx.x;
    const int tile0 = blockIdx.x * (NTH * PPT);

    // prefetch coords for all PPT tiles up front (VMEM overlaps table load)
    float pxs[PPT], pys[PPT];
#pragma unroll
    for (int k = 0; k < PPT; ++k) {
        int p = tile0 + k * NTH + tid;
        int pc = min(p, npts - 1);
        pxs[k] = x[pc];
        pys[k] = y[pc];
    }
    __syncthreads();   // table (and stage reuse) visible to all

#pragma unroll
    for (int k = 0; k < PPT; ++k) {
        int base = tile0 + k * NTH;
        if (base >= npts) break;           // block-uniform
        float px = pxs[k], py = pys[k];
        float4 r0 = sample_level<8 >(lds + OFF0, px, py);
        float4 r1 = sample_level<12>(lds + OFF1, px, py);
        float4 r2 = sample_level<20>(lds + OFF2, px, py);
        float4 r3 = sample_level<18>(lds + OFF3, px, py);
        float4 r4 = sample_level<32>(lds + OFF4, px, py);
        float4* srow = (float4*)(stage + tid * 20);
        srow[0] = r0; srow[1] = r1; srow[2] = r2; srow[3] = r3; srow[4] = r4;
        __syncthreads();
        // coalesced tile copy: consecutive lanes -> consecutive float4
        int validf4 = min(NTH, npts - base) * 5;
        float4* dst = (float4*)(out + (size_t)base * 20);
        const float4* s4 = (const float4*)stage;
        for (int j = tid; j < validf4; j += NTH)
            dst[j] = s4[j];
        __syncthreads();   // protect stage before next tile's writes
    }
}

__global__ __launch_bounds__(NTH, 4) void sample_kernel(const float* __restrict__ x,
                                                        const float* __restrict__ y,
                                                        const __half* __restrict__ tab,
                                                        float* __restrict__ out, int npts)
{
    __shared__ __align__(16) __half lds[PTOT];        // 34,256 B
    __shared__ __align__(16) float  stage[NTH * 20];  // 20,480 B -> 2 blk/CU
    const uint4* g4 = (const uint4*)tab;
    uint4* l4 = (uint4*)lds;
    for (int i = threadIdx.x; i < PTOT * 2 / 16; i += NTH)
        l4[i] = g4[i];
    sample_body(lds, stage, x, y, out, npts);   // does the barrier itself
}

// Fallback if workspace is too small: conv recomputed per block into LDS.
__global__ __launch_bounds__(NTH, 4) void fused_kernel(const float* __restrict__ x,
                                                       const float* __restrict__ y,
                                                       const float* __restrict__ F0,
                                                       const float* __restrict__ F1,
                                                       const float* __restrict__ F2,
                                                       const float* __restrict__ F3,
                                                       const float* __restrict__ F4,
                                                       const float* __restrict__ w,
                                                       float* __restrict__ out, int npts)
{
    __shared__ __align__(16) __half lds[PTOT];
    __shared__ __align__(16) float  stage[NTH * 20];
    conv_level<8 >(F0, w, lds + OFF0, threadIdx.x, NTH);
    conv_level<12>(F1, w, lds + OFF1, threadIdx.x, NTH);
    conv_level<20>(F2, w, lds + OFF2, threadIdx.x, NTH);
    conv_level<18>(F3, w, lds + OFF3, threadIdx.x, NTH);
    conv_level<32>(F4, w, lds + OFF4, threadIdx.x, NTH);
    sample_body(lds, stage, x, y, out, npts);
}

extern "C" void kernel_launch(void* const* d_in, const int* in_sizes, int n_in,
                              void* d_out, int out_size, void* d_ws, size_t ws_size,
                              hipStream_t stream)
{
    const float* x  = (const float*)d_in[0];
    const float* y  = (const float*)d_in[1];
    const float* w  = (const float*)d_in[2];
    const float* F0 = (const float*)d_in[3];
    const float* F1 = (const float*)d_in[4];
    const float* F2 = (const float*)d_in[5];
    const float* F3 = (const float*)d_in[6];
    const float* F4 = (const float*)d_in[7];
    float* out = (float*)d_out;
    int npts = in_sizes[0];

    int nb = (npts + NTH * PPT - 1) / (NTH * PPT);

    if (ws_size >= (size_t)PTOT * sizeof(__half)) {
        __half* tab = (__half*)d_ws;
        conv_kernel<<<(PTOT + 255) / 256, 256, 0, stream>>>(F0, F1, F2, F3, F4, w, tab);
        sample_kernel<<<nb, NTH, 0, stream>>>(x, y, tab, out, npts);
    } else {
        fused_kernel<<<nb, NTH, 0, stream>>>(x, y, F0, F1, F2, F3, F4, w, out, npts);
    }
}